// Round 2
// 498.603 us; speedup vs baseline: 1.0270x; 1.0270x over previous
//
#include <hip/hip_runtime.h>
#include <math.h>

constexpr int BATCH = 8;
constexpr int SEQ   = 2048;
constexpr int DIM   = 512;

typedef _Float16 f16x8  __attribute__((ext_vector_type(8)));
typedef float    f32x4  __attribute__((ext_vector_type(4)));
typedef float    f32x16 __attribute__((ext_vector_type(16)));

__device__ __forceinline__ void gload_lds16(const void* g, void* l) {
    __builtin_amdgcn_global_load_lds(
        (const __attribute__((address_space(1))) void*)g,
        (__attribute__((address_space(3))) void*)l, 16, 0, 0);
}

// ---------------------------------------------------------------------------
// fp16 NT MFMA GEMM: C[m,n] = alpha * sum_k A[m,k]*B[n,k]; A,B row-major fp16.
// Block tile 128x256, BK=64. 4 waves in 2x2; wave tile 64x128 = 2x4 tiles of
// v_mfma_f32_32x32x16_f16. Staging via global_load_lds (16B/lane), K-loop is
// pure ds_read_b128 + MFMA (m97 structure).
// XCD-aware bijective swizzle: dispatch index d -> XCD d%8 (HW round-robin);
// remap so each XCD gets a CONTIGUOUS tile range (T1). All grids are %8==0.
// ---------------------------------------------------------------------------
template<bool OUT_F16>
__global__ __launch_bounds__(256, 2) void gemm_nt_f16(
    const _Float16* __restrict__ A, int lda, long sA,
    const _Float16* __restrict__ B, int ldb, long sB,
    void* __restrict__ Cv, int ldc, long sC,
    int K, float alpha)
{
    // LDS frag layout: [k-chunk][row][8 fp16] — 16B per (chunk,row), contiguous
    // in row so a wave's 64 lanes land at base + lane*16 (global_load_lds rule).
    __shared__ _Float16 As[8][128][8];   // 16 KB
    __shared__ _Float16 Bs[8][256][8];   // 32 KB

    // XCD swizzle (bijective; nwg % 8 == 0 for every launch of this kernel)
    int lin = blockIdx.x + gridDim.x * (blockIdx.y + gridDim.y * blockIdx.z);
    const int nwg = gridDim.x * gridDim.y * gridDim.z;
    lin = (lin & 7) * (nwg >> 3) + (lin >> 3);
    const int bx  = lin % gridDim.x;
    const int byz = lin / gridDim.x;
    const int by  = byz % gridDim.y;
    const int bz  = byz / gridDim.y;

    A += (long)bz * sA;  B += (long)bz * sB;
    const long bm = (long)by * 128;
    const long bn = (long)bx * 256;
    const int t    = threadIdx.x;
    const int lane = t & 63;
    const int wave = t >> 6;
    const int wm = (wave >> 1) * 64;    // wave m-origin (2 tiles of 32)
    const int wn = (wave & 1) * 128;    // wave n-origin (4 tiles of 32)
    const int ml = lane & 31;
    const int kh = lane >> 5;           // k-half selector

    f32x16 acc[2][4] = {};

    for (int k0 = 0; k0 < K; k0 += 64) {
        // stage A: 8 chunks x 2 row-halves = 16 wave-segments, 4 per wave
#pragma unroll
        for (int s = 0; s < 4; s++) {
            const int idx = wave * 4 + s;
            const int ch  = idx >> 1;
            const int r0  = (idx & 1) * 64;
            const _Float16* gp = A + (bm + r0 + lane) * (long)lda + k0 + ch * 8;
            gload_lds16(gp, &As[ch][r0][0]);
        }
        // stage B: 8 chunks x 4 row-quarters = 32 wave-segments, 8 per wave
#pragma unroll
        for (int s = 0; s < 8; s++) {
            const int idx = wave * 8 + s;
            const int ch  = idx >> 2;
            const int r0  = (idx & 3) * 64;
            const _Float16* gp = B + (bn + r0 + lane) * (long)ldb + k0 + ch * 8;
            gload_lds16(gp, &Bs[ch][r0][0]);
        }
        __syncthreads();   // drains vmcnt -> LDS tiles valid

#pragma unroll
        for (int ks = 0; ks < 4; ks++) {
            const int ch = ks * 2 + kh;
            f16x8 a0 = *(const f16x8*)&As[ch][wm      + ml][0];
            f16x8 a1 = *(const f16x8*)&As[ch][wm + 32 + ml][0];
            f16x8 b0 = *(const f16x8*)&Bs[ch][wn       + ml][0];
            f16x8 b1 = *(const f16x8*)&Bs[ch][wn + 32  + ml][0];
            f16x8 b2 = *(const f16x8*)&Bs[ch][wn + 64  + ml][0];
            f16x8 b3 = *(const f16x8*)&Bs[ch][wn + 96  + ml][0];
            acc[0][0] = __builtin_amdgcn_mfma_f32_32x32x16_f16(a0, b0, acc[0][0], 0, 0, 0);
            acc[0][1] = __builtin_amdgcn_mfma_f32_32x32x16_f16(a0, b1, acc[0][1], 0, 0, 0);
            acc[0][2] = __builtin_amdgcn_mfma_f32_32x32x16_f16(a0, b2, acc[0][2], 0, 0, 0);
            acc[0][3] = __builtin_amdgcn_mfma_f32_32x32x16_f16(a0, b3, acc[0][3], 0, 0, 0);
            acc[1][0] = __builtin_amdgcn_mfma_f32_32x32x16_f16(a1, b0, acc[1][0], 0, 0, 0);
            acc[1][1] = __builtin_amdgcn_mfma_f32_32x32x16_f16(a1, b1, acc[1][1], 0, 0, 0);
            acc[1][2] = __builtin_amdgcn_mfma_f32_32x32x16_f16(a1, b2, acc[1][2], 0, 0, 0);
            acc[1][3] = __builtin_amdgcn_mfma_f32_32x32x16_f16(a1, b3, acc[1][3], 0, 0, 0);
        }
        __syncthreads();   // all LDS reads done before next iter's DMA
    }

    // Epilogue. C/D layout: col = lane&31; row = (rg&3) + 8*(rg>>2) + 4*(lane>>5)
    // fp32 outputs are final (never re-read) -> nontemporal stores.
    float*    Cf = (float*)Cv    + (OUT_F16 ? 0 : (long)bz * sC);
    _Float16* Ch = (_Float16*)Cv + (OUT_F16 ? (long)bz * sC : 0);
#pragma unroll
    for (int i = 0; i < 2; i++)
#pragma unroll
        for (int j = 0; j < 4; j++) {
            const long col = bn + wn + j * 32 + ml;
#pragma unroll
            for (int rg = 0; rg < 16; rg++) {
                const long row = bm + wm + i * 32 + (rg & 3) + 8 * (rg >> 2) + 4 * kh;
                if constexpr (OUT_F16)
                    Ch[row * (long)ldc + col] = (_Float16)(alpha * acc[i][j][rg]);
                else
                    __builtin_nontemporal_store(alpha * acc[i][j][rg],
                                                &Cf[row * (long)ldc + col]);
            }
        }
}

// ---------------------------------------------------------------------------
// Small fp32 TN GEMM: C[i,j] = alpha * sum_e A[e,i]*B[e,j] -> fp16 out.
// (P = c^2 Wk^T Wq). 512^3 only — accuracy anchor, fp32 vector math.
// ---------------------------------------------------------------------------
__global__ __launch_bounds__(256) void gemm_tn_f32(
    const float* __restrict__ A, int lda,
    const float* __restrict__ B, int ldb,
    _Float16* __restrict__ C, int ldc, int K, float alpha)
{
    __shared__ float As[16][68];
    __shared__ float Bs[16][68];
    const int bm = blockIdx.y * 64;
    const int bn = blockIdx.x * 64;
    const int t  = threadIdx.x;
    const int tx = t & 15, ty = t >> 4;
    const int kk = t >> 4, mc = (t & 15) * 4;

    float acc[4][4] = {};
    for (int k0 = 0; k0 < K; k0 += 16) {
        float4 a = *(const float4*)(A + (long)(k0 + kk) * lda + bm + mc);
        float4 b = *(const float4*)(B + (long)(k0 + kk) * ldb + bn + mc);
        __syncthreads();
        As[kk][mc] = a.x; As[kk][mc + 1] = a.y; As[kk][mc + 2] = a.z; As[kk][mc + 3] = a.w;
        Bs[kk][mc] = b.x; Bs[kk][mc + 1] = b.y; Bs[kk][mc + 2] = b.z; Bs[kk][mc + 3] = b.w;
        __syncthreads();
#pragma unroll
        for (int k = 0; k < 16; k++) {
            float ar[4], br[4];
#pragma unroll
            for (int i = 0; i < 4; i++) ar[i] = As[k][ty * 4 + i];
#pragma unroll
            for (int j = 0; j < 4; j++) br[j] = Bs[k][tx * 4 + j];
#pragma unroll
            for (int i = 0; i < 4; i++)
#pragma unroll
                for (int j = 0; j < 4; j++) acc[i][j] = fmaf(ar[i], br[j], acc[i][j]);
        }
    }
#pragma unroll
    for (int i = 0; i < 4; i++)
#pragma unroll
        for (int j = 0; j < 4; j++)
            C[(long)(bm + ty * 4 + i) * ldc + bn + tx * 4 + j] =
                (_Float16)(alpha * acc[i][j]);
}

// Row softmax over fp16 unnormalized dots. Reads fp16 (67 MB), writes fp32
// attn (required output, nontemporal — never re-read) and normalizes the fp16
// buffer IN PLACE for the PV GEMM. One block (256 thr) per row of 2048.
__global__ __launch_bounds__(256) void softmax_rows(
    _Float16* __restrict__ dots, float* __restrict__ attn)
{
    const long row = blockIdx.x;
    _Float16* ph = dots + row * (long)SEQ + threadIdx.x * 8;
    float*    pf = attn + row * (long)SEQ + threadIdx.x * 8;
    const int t = threadIdx.x;

    f16x8 h = *(const f16x8*)ph;
    float x[8];
#pragma unroll
    for (int i = 0; i < 8; i++) x[i] = (float)h[i];

    float m = x[0];
#pragma unroll
    for (int i = 1; i < 8; i++) m = fmaxf(m, x[i]);
#pragma unroll
    for (int off = 32; off > 0; off >>= 1) m = fmaxf(m, __shfl_xor(m, off));
    __shared__ float sm[4];
    __shared__ float ss[4];
    const int wave = t >> 6;
    if ((t & 63) == 0) sm[wave] = m;
    __syncthreads();
    m = fmaxf(fmaxf(sm[0], sm[1]), fmaxf(sm[2], sm[3]));

    float s = 0.0f;
#pragma unroll
    for (int i = 0; i < 8; i++) { x[i] = __expf(x[i] - m); s += x[i]; }
#pragma unroll
    for (int off = 32; off > 0; off >>= 1) s += __shfl_xor(s, off);
    if ((t & 63) == 0) ss[wave] = s;
    __syncthreads();
    s = ss[0] + ss[1] + ss[2] + ss[3];
    const float inv = 1.0f / s;

    f32x4 o0, o1;
    o0[0] = x[0] * inv; o0[1] = x[1] * inv; o0[2] = x[2] * inv; o0[3] = x[3] * inv;
    o1[0] = x[4] * inv; o1[1] = x[5] * inv; o1[2] = x[6] * inv; o1[3] = x[7] * inv;
    f32x4* pv = (f32x4*)pf;
    __builtin_nontemporal_store(o0, pv);
    __builtin_nontemporal_store(o1, pv + 1);

    f16x8 hn;
    hn[0] = (_Float16)o0[0]; hn[1] = (_Float16)o0[1];
    hn[2] = (_Float16)o0[2]; hn[3] = (_Float16)o0[3];
    hn[4] = (_Float16)o1[0]; hn[5] = (_Float16)o1[1];
    hn[6] = (_Float16)o1[2]; hn[7] = (_Float16)o1[3];
    *(f16x8*)ph = hn;
}

// Fused fp32 -> fp16 conversion of q | k | v | Wv in one launch.
// Index i is in units of 8 elements; range boundaries are block-aligned
// (1048576 / (256 thr) = 4096 blocks each), so branches are block-uniform.
__global__ __launch_bounds__(256) void conv_all(
    const float* __restrict__ q, const float* __restrict__ k,
    const float* __restrict__ v, const float* __restrict__ Wv,
    _Float16* __restrict__ q16, _Float16* __restrict__ k16,
    _Float16* __restrict__ v16, _Float16* __restrict__ Wv16)
{
    int i = blockIdx.x * 256 + threadIdx.x;
    const float* src; _Float16* dst;
    if (i < 1048576)      { src = q;  dst = q16; }
    else if (i < 2097152) { src = k;  dst = k16;  i -= 1048576; }
    else if (i < 3145728) { src = v;  dst = v16;  i -= 2097152; }
    else                  { src = Wv; dst = Wv16; i -= 3145728; }
    const float4 a = ((const float4*)src)[2 * i];
    const float4 b = ((const float4*)src)[2 * i + 1];
    f16x8 h;
    h[0] = (_Float16)a.x; h[1] = (_Float16)a.y; h[2] = (_Float16)a.z; h[3] = (_Float16)a.w;
    h[4] = (_Float16)b.x; h[5] = (_Float16)b.y; h[6] = (_Float16)b.z; h[7] = (_Float16)b.w;
    ((f16x8*)dst)[i] = h;
}

extern "C" void kernel_launch(void* const* d_in, const int* in_sizes, int n_in,
                              void* d_out, int out_size, void* d_ws, size_t ws_size,
                              hipStream_t stream)
{
    const float* q  = (const float*)d_in[0];
    const float* k  = (const float*)d_in[1];
    const float* v  = (const float*)d_in[2];
    const float* Wq = (const float*)d_in[3];
    const float* Wk = (const float*)d_in[4];
    const float* Wv = (const float*)d_in[5];

    float* out  = (float*)d_out;                                 // [8,2048,512]
    float* attn = (float*)d_out + (size_t)BATCH * SEQ * DIM;     // [8,2048,2048]

    // Workspace layout (bytes), peak 135 MB. dots16 (67 MB, written by K3,
    // normalized in place by softmax, read by K6) overlays only q16 (dead
    // after K2). Everything else disjoint.
    char* w = (char*)d_ws;
    _Float16* q16    = (_Float16*)(w);                           // 16.8 MB (head of dots16)
    _Float16* dots16 = (_Float16*)(w);                           // 67.1 MB
    _Float16* k16    = (_Float16*)(w + 67108864);                // 16.8 MB
    _Float16* v16    = (_Float16*)(w + 83886080);                // 16.8 MB
    _Float16* T16    = (_Float16*)(w + 100663296);               // 16.8 MB
    _Float16* vpT16  = (_Float16*)(w + 117440512);               // 16.8 MB
    _Float16* Wv16   = (_Float16*)(w + 134217728);               // 0.5 MB
    _Float16* P16    = (_Float16*)(w + 134742016);               // 0.5 MB

    const float c = 0.044194173824159216f;  // 1/sqrt(512)

    // K0: fp32 -> fp16 pre-conversion (q,k,v,Wv fused)
    conv_all<<<dim3(12416), 256, 0, stream>>>(q, k, v, Wv, q16, k16, v16, Wv16);

    // K1: P[d',d] = c^2 * sum_e Wk[e,d']*Wq[e,d]  (fp32 math, fp16 out)
    gemm_tn_f32<<<dim3(8, 8), 256, 0, stream>>>(Wk, DIM, Wq, DIM, P16, DIM, DIM, c * c);

    // K2: T[n,d'] = sum_d q[n,d]*P[d',d]  -> fp16 T  (M=16384, N=512, K=512)
    gemm_nt_f16<true><<<dim3(2, 128, 1), 256, 0, stream>>>(
        q16, DIM, 0, P16, DIM, 0, T16, DIM, 0, DIM, 1.0f);

    // K3: dots[n,m] = c * sum_d' T[n,d']*k[m,d']  per batch -> fp16 dots
    //     (unnormalized; overlays dead q16 region)
    gemm_nt_f16<true><<<dim3(8, 16, 8), 256, 0, stream>>>(
        T16, DIM, (long)SEQ * DIM, k16, DIM, (long)SEQ * DIM,
        dots16, SEQ, (long)SEQ * SEQ, DIM, c);

    // K5: vpT[e,m] = c * sum_d Wv[e,d]*v[m,d]  per batch -> fp16 [512,2048]
    gemm_nt_f16<true><<<dim3(8, 4, 8), 256, 0, stream>>>(
        Wv16, DIM, 0, v16, DIM, (long)SEQ * DIM,
        vpT16, SEQ, (long)DIM * SEQ, DIM, c);

    // K4: softmax — fp16 dots in, fp32 attn out (NT) + fp16 normalize in place
    softmax_rows<<<dim3(BATCH * SEQ), 256, 0, stream>>>(dots16, attn);

    // K6: out[n,e] = sum_m attn[n,m]*vpT[e,m]  per batch -> fp32 out (NT)
    gemm_nt_f16<false><<<dim3(2, 16, 8), 256, 0, stream>>>(
        dots16, SEQ, (long)SEQ * SEQ, vpT16, SEQ, (long)DIM * SEQ,
        out, DIM, (long)SEQ * DIM, SEQ, 1.0f);
}

// Round 3
// 494.924 us; speedup vs baseline: 1.0347x; 1.0074x over previous
//
#include <hip/hip_runtime.h>
#include <math.h>

constexpr int BATCH = 8;
constexpr int SEQ   = 2048;
constexpr int DIM   = 512;

typedef _Float16 f16x8  __attribute__((ext_vector_type(8)));
typedef float    f32x4  __attribute__((ext_vector_type(4)));
typedef float    f32x16 __attribute__((ext_vector_type(16)));

__device__ __forceinline__ void gload_lds16(const void* g, void* l) {
    __builtin_amdgcn_global_load_lds(
        (const __attribute__((address_space(1))) void*)g,
        (__attribute__((address_space(3))) void*)l, 16, 0, 0);
}

// ---------------------------------------------------------------------------
// fp16 NT MFMA GEMM: C[m,n] = alpha * sum_k A[m,k]*B[n,k]; A,B row-major fp16.
// Block tile 128x128, BK=64. 4 waves in 2x2; wave tile 64x64 = 2x2 tiles of
// v_mfma_f32_32x32x16_f16. Staging via global_load_lds (16B/lane), K-loop is
// pure ds_read_b128 + MFMA (m97 structure; 128^2 = proven best tile for the
// 2-barrier loop: m103 912 TF vs m105 823 TF at 128x256). 32 KB LDS + ~130
// VGPR -> 3 blocks/CU (launch_bounds(256,3)) to hide the barrier drain.
// XCD-aware bijective swizzle: all grids are %8==0.
// ---------------------------------------------------------------------------
template<bool OUT_F16>
__global__ __launch_bounds__(256, 3) void gemm_nt_f16(
    const _Float16* __restrict__ A, int lda, long sA,
    const _Float16* __restrict__ B, int ldb, long sB,
    void* __restrict__ Cv, int ldc, long sC,
    int K, float alpha)
{
    // LDS frag layout: [k-chunk][row][8 fp16] — 16B per (chunk,row), contiguous
    // in row so a wave's 64 lanes land at base + lane*16 (global_load_lds rule).
    __shared__ _Float16 As[8][128][8];   // 16 KB
    __shared__ _Float16 Bs[8][128][8];   // 16 KB

    // XCD swizzle (bijective; nwg % 8 == 0 for every launch of this kernel)
    int lin = blockIdx.x + gridDim.x * (blockIdx.y + gridDim.y * blockIdx.z);
    const int nwg = gridDim.x * gridDim.y * gridDim.z;
    lin = (lin & 7) * (nwg >> 3) + (lin >> 3);
    const int bx  = lin % gridDim.x;
    const int byz = lin / gridDim.x;
    const int by  = byz % gridDim.y;
    const int bz  = byz / gridDim.y;

    A += (long)bz * sA;  B += (long)bz * sB;
    const long bm = (long)by * 128;
    const long bn = (long)bx * 128;
    const int t    = threadIdx.x;
    const int lane = t & 63;
    const int wave = t >> 6;
    const int wm = (wave >> 1) * 64;    // wave m-origin (2 tiles of 32)
    const int wn = (wave & 1) * 64;     // wave n-origin (2 tiles of 32)
    const int ml = lane & 31;
    const int kh = lane >> 5;           // k-half selector

    f32x16 acc[2][2] = {};

    for (int k0 = 0; k0 < K; k0 += 64) {
        // stage A: 8 chunks x 2 row-halves = 16 wave-segments, 4 per wave
#pragma unroll
        for (int s = 0; s < 4; s++) {
            const int idx = wave * 4 + s;
            const int ch  = idx >> 1;
            const int r0  = (idx & 1) * 64;
            const _Float16* gp = A + (bm + r0 + lane) * (long)lda + k0 + ch * 8;
            gload_lds16(gp, &As[ch][r0][0]);
        }
        // stage B: same decomposition
#pragma unroll
        for (int s = 0; s < 4; s++) {
            const int idx = wave * 4 + s;
            const int ch  = idx >> 1;
            const int r0  = (idx & 1) * 64;
            const _Float16* gp = B + (bn + r0 + lane) * (long)ldb + k0 + ch * 8;
            gload_lds16(gp, &Bs[ch][r0][0]);
        }
        __syncthreads();   // drains vmcnt -> LDS tiles valid

#pragma unroll
        for (int ks = 0; ks < 4; ks++) {
            const int ch = ks * 2 + kh;
            f16x8 a0 = *(const f16x8*)&As[ch][wm      + ml][0];
            f16x8 a1 = *(const f16x8*)&As[ch][wm + 32 + ml][0];
            f16x8 b0 = *(const f16x8*)&Bs[ch][wn      + ml][0];
            f16x8 b1 = *(const f16x8*)&Bs[ch][wn + 32 + ml][0];
            acc[0][0] = __builtin_amdgcn_mfma_f32_32x32x16_f16(a0, b0, acc[0][0], 0, 0, 0);
            acc[0][1] = __builtin_amdgcn_mfma_f32_32x32x16_f16(a0, b1, acc[0][1], 0, 0, 0);
            acc[1][0] = __builtin_amdgcn_mfma_f32_32x32x16_f16(a1, b0, acc[1][0], 0, 0, 0);
            acc[1][1] = __builtin_amdgcn_mfma_f32_32x32x16_f16(a1, b1, acc[1][1], 0, 0, 0);
        }
        __syncthreads();   // all LDS reads done before next iter's DMA
    }

    // Epilogue. C/D layout: col = lane&31; row = (rg&3) + 8*(rg>>2) + 4*(lane>>5)
    // fp32 outputs are final (never re-read) -> nontemporal stores.
    float*    Cf = (float*)Cv    + (OUT_F16 ? 0 : (long)bz * sC);
    _Float16* Ch = (_Float16*)Cv + (OUT_F16 ? (long)bz * sC : 0);
#pragma unroll
    for (int i = 0; i < 2; i++)
#pragma unroll
        for (int j = 0; j < 2; j++) {
            const long col = bn + wn + j * 32 + ml;
#pragma unroll
            for (int rg = 0; rg < 16; rg++) {
                const long row = bm + wm + i * 32 + (rg & 3) + 8 * (rg >> 2) + 4 * kh;
                if constexpr (OUT_F16)
                    Ch[row * (long)ldc + col] = (_Float16)(alpha * acc[i][j][rg]);
                else
                    __builtin_nontemporal_store(alpha * acc[i][j][rg],
                                                &Cf[row * (long)ldc + col]);
            }
        }
}

// ---------------------------------------------------------------------------
// Small fp32 TN GEMM: C[i,j] = alpha * sum_e A[e,i]*B[e,j] -> fp16 out.
// (P = c^2 Wk^T Wq). 512^3 only — accuracy anchor, fp32 vector math.
// ---------------------------------------------------------------------------
__global__ __launch_bounds__(256) void gemm_tn_f32(
    const float* __restrict__ A, int lda,
    const float* __restrict__ B, int ldb,
    _Float16* __restrict__ C, int ldc, int K, float alpha)
{
    __shared__ float As[16][68];
    __shared__ float Bs[16][68];
    const int bm = blockIdx.y * 64;
    const int bn = blockIdx.x * 64;
    const int t  = threadIdx.x;
    const int tx = t & 15, ty = t >> 4;
    const int kk = t >> 4, mc = (t & 15) * 4;

    float acc[4][4] = {};
    for (int k0 = 0; k0 < K; k0 += 16) {
        float4 a = *(const float4*)(A + (long)(k0 + kk) * lda + bm + mc);
        float4 b = *(const float4*)(B + (long)(k0 + kk) * ldb + bn + mc);
        __syncthreads();
        As[kk][mc] = a.x; As[kk][mc + 1] = a.y; As[kk][mc + 2] = a.z; As[kk][mc + 3] = a.w;
        Bs[kk][mc] = b.x; Bs[kk][mc + 1] = b.y; Bs[kk][mc + 2] = b.z; Bs[kk][mc + 3] = b.w;
        __syncthreads();
#pragma unroll
        for (int k = 0; k < 16; k++) {
            float ar[4], br[4];
#pragma unroll
            for (int i = 0; i < 4; i++) ar[i] = As[k][ty * 4 + i];
#pragma unroll
            for (int j = 0; j < 4; j++) br[j] = Bs[k][tx * 4 + j];
#pragma unroll
            for (int i = 0; i < 4; i++)
#pragma unroll
                for (int j = 0; j < 4; j++) acc[i][j] = fmaf(ar[i], br[j], acc[i][j]);
        }
    }
#pragma unroll
    for (int i = 0; i < 4; i++)
#pragma unroll
        for (int j = 0; j < 4; j++)
            C[(long)(bm + ty * 4 + i) * ldc + bn + tx * 4 + j] =
                (_Float16)(alpha * acc[i][j]);
}

// Row softmax over fp16 unnormalized dots. Reads fp16 (67 MB), writes fp32
// attn (required output, nontemporal — never re-read) and normalizes the fp16
// buffer IN PLACE for the PV GEMM. One block (256 thr) per row of 2048.
__global__ __launch_bounds__(256) void softmax_rows(
    _Float16* __restrict__ dots, float* __restrict__ attn)
{
    const long row = blockIdx.x;
    _Float16* ph = dots + row * (long)SEQ + threadIdx.x * 8;
    float*    pf = attn + row * (long)SEQ + threadIdx.x * 8;
    const int t = threadIdx.x;

    f16x8 h = *(const f16x8*)ph;
    float x[8];
#pragma unroll
    for (int i = 0; i < 8; i++) x[i] = (float)h[i];

    float m = x[0];
#pragma unroll
    for (int i = 1; i < 8; i++) m = fmaxf(m, x[i]);
#pragma unroll
    for (int off = 32; off > 0; off >>= 1) m = fmaxf(m, __shfl_xor(m, off));
    __shared__ float sm[4];
    __shared__ float ss[4];
    const int wave = t >> 6;
    if ((t & 63) == 0) sm[wave] = m;
    __syncthreads();
    m = fmaxf(fmaxf(sm[0], sm[1]), fmaxf(sm[2], sm[3]));

    float s = 0.0f;
#pragma unroll
    for (int i = 0; i < 8; i++) { x[i] = __expf(x[i] - m); s += x[i]; }
#pragma unroll
    for (int off = 32; off > 0; off >>= 1) s += __shfl_xor(s, off);
    if ((t & 63) == 0) ss[wave] = s;
    __syncthreads();
    s = ss[0] + ss[1] + ss[2] + ss[3];
    const float inv = 1.0f / s;

    f32x4 o0, o1;
    o0[0] = x[0] * inv; o0[1] = x[1] * inv; o0[2] = x[2] * inv; o0[3] = x[3] * inv;
    o1[0] = x[4] * inv; o1[1] = x[5] * inv; o1[2] = x[6] * inv; o1[3] = x[7] * inv;
    f32x4* pv = (f32x4*)pf;
    __builtin_nontemporal_store(o0, pv);
    __builtin_nontemporal_store(o1, pv + 1);

    f16x8 hn;
    hn[0] = (_Float16)o0[0]; hn[1] = (_Float16)o0[1];
    hn[2] = (_Float16)o0[2]; hn[3] = (_Float16)o0[3];
    hn[4] = (_Float16)o1[0]; hn[5] = (_Float16)o1[1];
    hn[6] = (_Float16)o1[2]; hn[7] = (_Float16)o1[3];
    *(f16x8*)ph = hn;
}

// Fused fp32 -> fp16 conversion of q | k | v | Wv in one launch.
// Index i is in units of 8 elements; range boundaries are block-aligned
// (1048576 / (256 thr) = 4096 blocks each), so branches are block-uniform.
__global__ __launch_bounds__(256) void conv_all(
    const float* __restrict__ q, const float* __restrict__ k,
    const float* __restrict__ v, const float* __restrict__ Wv,
    _Float16* __restrict__ q16, _Float16* __restrict__ k16,
    _Float16* __restrict__ v16, _Float16* __restrict__ Wv16)
{
    int i = blockIdx.x * 256 + threadIdx.x;
    const float* src; _Float16* dst;
    if (i < 1048576)      { src = q;  dst = q16; }
    else if (i < 2097152) { src = k;  dst = k16;  i -= 1048576; }
    else if (i < 3145728) { src = v;  dst = v16;  i -= 2097152; }
    else                  { src = Wv; dst = Wv16; i -= 3145728; }
    const float4 a = ((const float4*)src)[2 * i];
    const float4 b = ((const float4*)src)[2 * i + 1];
    f16x8 h;
    h[0] = (_Float16)a.x; h[1] = (_Float16)a.y; h[2] = (_Float16)a.z; h[3] = (_Float16)a.w;
    h[4] = (_Float16)b.x; h[5] = (_Float16)b.y; h[6] = (_Float16)b.z; h[7] = (_Float16)b.w;
    ((f16x8*)dst)[i] = h;
}

extern "C" void kernel_launch(void* const* d_in, const int* in_sizes, int n_in,
                              void* d_out, int out_size, void* d_ws, size_t ws_size,
                              hipStream_t stream)
{
    const float* q  = (const float*)d_in[0];
    const float* k  = (const float*)d_in[1];
    const float* v  = (const float*)d_in[2];
    const float* Wq = (const float*)d_in[3];
    const float* Wk = (const float*)d_in[4];
    const float* Wv = (const float*)d_in[5];

    float* out  = (float*)d_out;                                 // [8,2048,512]
    float* attn = (float*)d_out + (size_t)BATCH * SEQ * DIM;     // [8,2048,2048]

    // Workspace layout (bytes), peak 135 MB. dots16 (67 MB, written by K3,
    // normalized in place by softmax, read by K6) overlays only q16 (dead
    // after K2). Everything else disjoint.
    char* w = (char*)d_ws;
    _Float16* q16    = (_Float16*)(w);                           // 16.8 MB (head of dots16)
    _Float16* dots16 = (_Float16*)(w);                           // 67.1 MB
    _Float16* k16    = (_Float16*)(w + 67108864);                // 16.8 MB
    _Float16* v16    = (_Float16*)(w + 83886080);                // 16.8 MB
    _Float16* T16    = (_Float16*)(w + 100663296);               // 16.8 MB
    _Float16* vpT16  = (_Float16*)(w + 117440512);               // 16.8 MB
    _Float16* Wv16   = (_Float16*)(w + 134217728);               // 0.5 MB
    _Float16* P16    = (_Float16*)(w + 134742016);               // 0.5 MB

    const float c = 0.044194173824159216f;  // 1/sqrt(512)

    // K0: fp32 -> fp16 pre-conversion (q,k,v,Wv fused)
    conv_all<<<dim3(12416), 256, 0, stream>>>(q, k, v, Wv, q16, k16, v16, Wv16);

    // K1: P[d',d] = c^2 * sum_e Wk[e,d']*Wq[e,d]  (fp32 math, fp16 out)
    gemm_tn_f32<<<dim3(8, 8), 256, 0, stream>>>(Wk, DIM, Wq, DIM, P16, DIM, DIM, c * c);

    // K2: T[n,d'] = sum_d q[n,d]*P[d',d]  -> fp16 T  (M=16384, N=512, K=512)
    gemm_nt_f16<true><<<dim3(4, 128, 1), 256, 0, stream>>>(
        q16, DIM, 0, P16, DIM, 0, T16, DIM, 0, DIM, 1.0f);

    // K3: dots[n,m] = c * sum_d' T[n,d']*k[m,d']  per batch -> fp16 dots
    //     (unnormalized; overlays dead q16 region)
    gemm_nt_f16<true><<<dim3(16, 16, 8), 256, 0, stream>>>(
        T16, DIM, (long)SEQ * DIM, k16, DIM, (long)SEQ * DIM,
        dots16, SEQ, (long)SEQ * SEQ, DIM, c);

    // K5: vpT[e,m] = c * sum_d Wv[e,d]*v[m,d]  per batch -> fp16 [512,2048]
    gemm_nt_f16<true><<<dim3(16, 4, 8), 256, 0, stream>>>(
        Wv16, DIM, 0, v16, DIM, (long)SEQ * DIM,
        vpT16, SEQ, (long)DIM * SEQ, DIM, c);

    // K4: softmax — fp16 dots in, fp32 attn out (NT) + fp16 normalize in place
    softmax_rows<<<dim3(BATCH * SEQ), 256, 0, stream>>>(dots16, attn);

    // K6: out[n,e] = sum_m attn[n,m]*vpT[e,m]  per batch -> fp32 out (NT)
    gemm_nt_f16<false><<<dim3(4, 16, 8), 256, 0, stream>>>(
        dots16, SEQ, (long)SEQ * SEQ, vpT16, SEQ, (long)DIM * SEQ,
        out, DIM, (long)SEQ * DIM, SEQ, 1.0f);
}

// Round 4
// 462.621 us; speedup vs baseline: 1.1069x; 1.0698x over previous
//
#include <hip/hip_runtime.h>
#include <math.h>

constexpr int BATCH = 8;
constexpr int SEQ   = 2048;
constexpr int DIM   = 512;

typedef _Float16 f16x8  __attribute__((ext_vector_type(8)));
typedef float    f32x4  __attribute__((ext_vector_type(4)));
typedef float    f32x16 __attribute__((ext_vector_type(16)));

__device__ __forceinline__ void gload_lds16(const void* g, void* l) {
    __builtin_amdgcn_global_load_lds(
        (const __attribute__((address_space(1))) void*)g,
        (__attribute__((address_space(3))) void*)l, 16, 0, 0);
}

// ---------------------------------------------------------------------------
// fp16 NT MFMA GEMM: C[m,n] = alpha * sum_k A[m,k]*B[n,k]; A,B row-major fp16.
// Block tile 128x128, BK=64. 4 waves in 2x2; wave tile 64x64 = 2x2 tiles of
// v_mfma_f32_32x32x16_f16. Staging via global_load_lds (16B/lane), K-loop is
// pure ds_read_b128 + MFMA (m97 structure). Short-K (8 steps) exposes the
// per-step barrier drain; the knob that works on this structure is co-resident
// blocks (TLP). 32 KB LDS -> up to 5 blocks/CU; VGPR ~110 fits 128-budget, so
// claim 4 blocks/CU (launch_bounds(256,4) = 4 waves/EU).
// XCD-aware bijective swizzle: all grids are %8==0. For K3/K6 this puts one
// batch per XCD (working set ~L2-sized).
// ---------------------------------------------------------------------------
template<bool OUT_F16>
__global__ __launch_bounds__(256, 4) void gemm_nt_f16(
    const _Float16* __restrict__ A, int lda, long sA,
    const _Float16* __restrict__ B, int ldb, long sB,
    void* __restrict__ Cv, int ldc, long sC,
    int K, float alpha)
{
    // LDS frag layout: [k-chunk][row][8 fp16] — 16B per (chunk,row), contiguous
    // in row so a wave's 64 lanes land at base + lane*16 (global_load_lds rule).
    // ds_read pattern: 64 lanes cover 32 consecutive 16B rows x 2 chunks ->
    // conflict-free (2-way chunk alias is free, m136).
    __shared__ _Float16 As[8][128][8];   // 16 KB
    __shared__ _Float16 Bs[8][128][8];   // 16 KB

    // XCD swizzle (bijective; nwg % 8 == 0 for every launch of this kernel)
    int lin = blockIdx.x + gridDim.x * (blockIdx.y + gridDim.y * blockIdx.z);
    const int nwg = gridDim.x * gridDim.y * gridDim.z;
    lin = (lin & 7) * (nwg >> 3) + (lin >> 3);
    const int bx  = lin % gridDim.x;
    const int byz = lin / gridDim.x;
    const int by  = byz % gridDim.y;
    const int bz  = byz / gridDim.y;

    A += (long)bz * sA;  B += (long)bz * sB;
    const long bm = (long)by * 128;
    const long bn = (long)bx * 128;
    const int t    = threadIdx.x;
    const int lane = t & 63;
    const int wave = t >> 6;
    const int wm = (wave >> 1) * 64;    // wave m-origin (2 tiles of 32)
    const int wn = (wave & 1) * 64;     // wave n-origin (2 tiles of 32)
    const int ml = lane & 31;
    const int kh = lane >> 5;           // k-half selector

    f32x16 acc[2][2] = {};

    for (int k0 = 0; k0 < K; k0 += 64) {
        // stage A: 8 chunks x 2 row-halves = 16 wave-segments, 4 per wave
#pragma unroll
        for (int s = 0; s < 4; s++) {
            const int idx = wave * 4 + s;
            const int ch  = idx >> 1;
            const int r0  = (idx & 1) * 64;
            const _Float16* gp = A + (bm + r0 + lane) * (long)lda + k0 + ch * 8;
            gload_lds16(gp, &As[ch][r0][0]);
        }
        // stage B: same decomposition
#pragma unroll
        for (int s = 0; s < 4; s++) {
            const int idx = wave * 4 + s;
            const int ch  = idx >> 1;
            const int r0  = (idx & 1) * 64;
            const _Float16* gp = B + (bn + r0 + lane) * (long)ldb + k0 + ch * 8;
            gload_lds16(gp, &Bs[ch][r0][0]);
        }
        __syncthreads();   // drains vmcnt -> LDS tiles valid

#pragma unroll
        for (int ks = 0; ks < 4; ks++) {
            const int ch = ks * 2 + kh;
            f16x8 a0 = *(const f16x8*)&As[ch][wm      + ml][0];
            f16x8 a1 = *(const f16x8*)&As[ch][wm + 32 + ml][0];
            f16x8 b0 = *(const f16x8*)&Bs[ch][wn      + ml][0];
            f16x8 b1 = *(const f16x8*)&Bs[ch][wn + 32 + ml][0];
            acc[0][0] = __builtin_amdgcn_mfma_f32_32x32x16_f16(a0, b0, acc[0][0], 0, 0, 0);
            acc[0][1] = __builtin_amdgcn_mfma_f32_32x32x16_f16(a0, b1, acc[0][1], 0, 0, 0);
            acc[1][0] = __builtin_amdgcn_mfma_f32_32x32x16_f16(a1, b0, acc[1][0], 0, 0, 0);
            acc[1][1] = __builtin_amdgcn_mfma_f32_32x32x16_f16(a1, b1, acc[1][1], 0, 0, 0);
        }
        __syncthreads();   // all LDS reads done before next iter's DMA
    }

    // Epilogue. C/D layout: col = lane&31; row = (rg&3) + 8*(rg>>2) + 4*(lane>>5)
    // fp32 outputs are final (never re-read) -> nontemporal stores.
    float*    Cf = (float*)Cv    + (OUT_F16 ? 0 : (long)bz * sC);
    _Float16* Ch = (_Float16*)Cv + (OUT_F16 ? (long)bz * sC : 0);
#pragma unroll
    for (int i = 0; i < 2; i++)
#pragma unroll
        for (int j = 0; j < 2; j++) {
            const long col = bn + wn + j * 32 + ml;
#pragma unroll
            for (int rg = 0; rg < 16; rg++) {
                const long row = bm + wm + i * 32 + (rg & 3) + 8 * (rg >> 2) + 4 * kh;
                if constexpr (OUT_F16)
                    Ch[row * (long)ldc + col] = (_Float16)(alpha * acc[i][j][rg]);
                else
                    __builtin_nontemporal_store(alpha * acc[i][j][rg],
                                                &Cf[row * (long)ldc + col]);
            }
        }
}

// ---------------------------------------------------------------------------
// Small fp32 TN GEMM, split-K: Cpart[s][i][j] = sum_{e in slice s} A[e,i]*B[e,j].
// (P = c^2 Wk^T Wq; fp32 math = accuracy anchor.) Old single-launch version was
// latency-bound (~64 blocks, 1 wave/SIMD, ~8192 FMA/thread). Split K=512 into
// 8 slices -> 512 blocks, ~1k FMA/thread; tiny reduce follows.
// ---------------------------------------------------------------------------
__global__ __launch_bounds__(256) void gemm_tn_f32_sk(
    const float* __restrict__ A, int lda,
    const float* __restrict__ B, int ldb,
    float* __restrict__ Cpart, int ldc)
{
    __shared__ float As[16][68];
    __shared__ float Bs[16][68];
    const int bm = blockIdx.y * 64;
    const int bn = blockIdx.x * 64;
    const int kb = blockIdx.z * 64;     // K-slice base, 64 deep
    const int t  = threadIdx.x;
    const int tx = t & 15, ty = t >> 4;
    const int kk = t >> 4, mc = (t & 15) * 4;

    float acc[4][4] = {};
    for (int k0 = kb; k0 < kb + 64; k0 += 16) {
        float4 a = *(const float4*)(A + (long)(k0 + kk) * lda + bm + mc);
        float4 b = *(const float4*)(B + (long)(k0 + kk) * ldb + bn + mc);
        __syncthreads();
        As[kk][mc] = a.x; As[kk][mc + 1] = a.y; As[kk][mc + 2] = a.z; As[kk][mc + 3] = a.w;
        Bs[kk][mc] = b.x; Bs[kk][mc + 1] = b.y; Bs[kk][mc + 2] = b.z; Bs[kk][mc + 3] = b.w;
        __syncthreads();
#pragma unroll
        for (int k = 0; k < 16; k++) {
            f32x4 ar = *(const f32x4*)&As[k][ty * 4];   // ds_read_b128
            f32x4 br = *(const f32x4*)&Bs[k][tx * 4];
#pragma unroll
            for (int i = 0; i < 4; i++)
#pragma unroll
                for (int j = 0; j < 4; j++) acc[i][j] = fmaf(ar[i], br[j], acc[i][j]);
        }
    }
    float* Cp = Cpart + (long)blockIdx.z * DIM * DIM;
#pragma unroll
    for (int i = 0; i < 4; i++)
#pragma unroll
        for (int j = 0; j < 4; j++)
            Cp[(long)(bm + ty * 4 + i) * ldc + bn + tx * 4 + j] = acc[i][j];
}

// Reduce 8 split-K partials -> P16 fp16 (with c^2 scale). 262144 elems.
__global__ __launch_bounds__(256) void reduce_p(
    const float* __restrict__ Cpart, _Float16* __restrict__ P, float alpha)
{
    const int idx = blockIdx.x * 256 + threadIdx.x;
    float s = 0.0f;
#pragma unroll
    for (int sl = 0; sl < 8; sl++) s += Cpart[(long)sl * DIM * DIM + idx];
    P[idx] = (_Float16)(alpha * s);
}

// Row softmax over fp16 unnormalized dots. Reads fp16 (67 MB), writes fp32
// attn (required output, nontemporal — never re-read) and normalizes the fp16
// buffer IN PLACE for the PV GEMM. One block (256 thr) per row of 2048.
__global__ __launch_bounds__(256) void softmax_rows(
    _Float16* __restrict__ dots, float* __restrict__ attn)
{
    const long row = blockIdx.x;
    _Float16* ph = dots + row * (long)SEQ + threadIdx.x * 8;
    float*    pf = attn + row * (long)SEQ + threadIdx.x * 8;
    const int t = threadIdx.x;

    f16x8 h = *(const f16x8*)ph;
    float x[8];
#pragma unroll
    for (int i = 0; i < 8; i++) x[i] = (float)h[i];

    float m = x[0];
#pragma unroll
    for (int i = 1; i < 8; i++) m = fmaxf(m, x[i]);
#pragma unroll
    for (int off = 32; off > 0; off >>= 1) m = fmaxf(m, __shfl_xor(m, off));
    __shared__ float sm[4];
    __shared__ float ss[4];
    const int wave = t >> 6;
    if ((t & 63) == 0) sm[wave] = m;
    __syncthreads();
    m = fmaxf(fmaxf(sm[0], sm[1]), fmaxf(sm[2], sm[3]));

    float s = 0.0f;
#pragma unroll
    for (int i = 0; i < 8; i++) { x[i] = __expf(x[i] - m); s += x[i]; }
#pragma unroll
    for (int off = 32; off > 0; off >>= 1) s += __shfl_xor(s, off);
    if ((t & 63) == 0) ss[wave] = s;
    __syncthreads();
    s = ss[0] + ss[1] + ss[2] + ss[3];
    const float inv = 1.0f / s;

    f32x4 o0, o1;
    o0[0] = x[0] * inv; o0[1] = x[1] * inv; o0[2] = x[2] * inv; o0[3] = x[3] * inv;
    o1[0] = x[4] * inv; o1[1] = x[5] * inv; o1[2] = x[6] * inv; o1[3] = x[7] * inv;
    f32x4* pv = (f32x4*)pf;
    __builtin_nontemporal_store(o0, pv);
    __builtin_nontemporal_store(o1, pv + 1);

    f16x8 hn;
    hn[0] = (_Float16)o0[0]; hn[1] = (_Float16)o0[1];
    hn[2] = (_Float16)o0[2]; hn[3] = (_Float16)o0[3];
    hn[4] = (_Float16)o1[0]; hn[5] = (_Float16)o1[1];
    hn[6] = (_Float16)o1[2]; hn[7] = (_Float16)o1[3];
    *(f16x8*)ph = hn;
}

// Fused fp32 -> fp16 conversion of q | k | v | Wv in one launch.
// Index i is in units of 8 elements; range boundaries are block-aligned
// (1048576 / (256 thr) = 4096 blocks each), so branches are block-uniform.
// Sources are read-once -> nontemporal loads.
__global__ __launch_bounds__(256) void conv_all(
    const float* __restrict__ q, const float* __restrict__ k,
    const float* __restrict__ v, const float* __restrict__ Wv,
    _Float16* __restrict__ q16, _Float16* __restrict__ k16,
    _Float16* __restrict__ v16, _Float16* __restrict__ Wv16)
{
    int i = blockIdx.x * 256 + threadIdx.x;
    const float* src; _Float16* dst;
    if (i < 1048576)      { src = q;  dst = q16; }
    else if (i < 2097152) { src = k;  dst = k16;  i -= 1048576; }
    else if (i < 3145728) { src = v;  dst = v16;  i -= 2097152; }
    else                  { src = Wv; dst = Wv16; i -= 3145728; }
    const f32x4 a = __builtin_nontemporal_load((const f32x4*)src + 2 * i);
    const f32x4 b = __builtin_nontemporal_load((const f32x4*)src + 2 * i + 1);
    f16x8 h;
    h[0] = (_Float16)a[0]; h[1] = (_Float16)a[1]; h[2] = (_Float16)a[2]; h[3] = (_Float16)a[3];
    h[4] = (_Float16)b[0]; h[5] = (_Float16)b[1]; h[6] = (_Float16)b[2]; h[7] = (_Float16)b[3];
    ((f16x8*)dst)[i] = h;
}

extern "C" void kernel_launch(void* const* d_in, const int* in_sizes, int n_in,
                              void* d_out, int out_size, void* d_ws, size_t ws_size,
                              hipStream_t stream)
{
    const float* q  = (const float*)d_in[0];
    const float* k  = (const float*)d_in[1];
    const float* v  = (const float*)d_in[2];
    const float* Wq = (const float*)d_in[3];
    const float* Wk = (const float*)d_in[4];
    const float* Wv = (const float*)d_in[5];

    float* out  = (float*)d_out;                                 // [8,2048,512]
    float* attn = (float*)d_out + (size_t)BATCH * SEQ * DIM;     // [8,2048,2048]

    // Workspace layout (bytes). dots16 (67 MB, written by K3, normalized in
    // place by softmax, read by K6) overlays only q16 (dead after K2).
    char* w = (char*)d_ws;
    _Float16* q16    = (_Float16*)(w);                           // 16.8 MB (head of dots16)
    _Float16* dots16 = (_Float16*)(w);                           // 67.1 MB
    _Float16* k16    = (_Float16*)(w + 67108864);                // 16.8 MB
    _Float16* v16    = (_Float16*)(w + 83886080);                // 16.8 MB
    _Float16* T16    = (_Float16*)(w + 100663296);               // 16.8 MB
    _Float16* vpT16  = (_Float16*)(w + 117440512);               // 16.8 MB
    _Float16* Wv16   = (_Float16*)(w + 134217728);               // 0.5 MB
    _Float16* P16    = (_Float16*)(w + 134742016);               // 0.5 MB
    float*    Ppart  = (float*)   (w + 201326592);               // 8 MB split-K scratch

    const float c = 0.044194173824159216f;  // 1/sqrt(512)

    // K0: fp32 -> fp16 pre-conversion (q,k,v,Wv fused)
    conv_all<<<dim3(12416), 256, 0, stream>>>(q, k, v, Wv, q16, k16, v16, Wv16);

    // K1a/K1b: P[d',d] = c^2 * sum_e Wk[e,d']*Wq[e,d]  (fp32 split-K + reduce)
    gemm_tn_f32_sk<<<dim3(8, 8, 8), 256, 0, stream>>>(Wk, DIM, Wq, DIM, Ppart, DIM);
    reduce_p<<<dim3(1024), 256, 0, stream>>>(Ppart, P16, c * c);

    // K2: T[n,d'] = sum_d q[n,d]*P[d',d]  -> fp16 T  (M=16384, N=512, K=512)
    gemm_nt_f16<true><<<dim3(4, 128, 1), 256, 0, stream>>>(
        q16, DIM, 0, P16, DIM, 0, T16, DIM, 0, DIM, 1.0f);

    // K3: dots[n,m] = c * sum_d' T[n,d']*k[m,d']  per batch -> fp16 dots
    //     (unnormalized; overlays dead q16 region)
    gemm_nt_f16<true><<<dim3(16, 16, 8), 256, 0, stream>>>(
        T16, DIM, (long)SEQ * DIM, k16, DIM, (long)SEQ * DIM,
        dots16, SEQ, (long)SEQ * SEQ, DIM, c);

    // K5: vpT[e,m] = c * sum_d Wv[e,d]*v[m,d]  per batch -> fp16 [512,2048]
    gemm_nt_f16<true><<<dim3(16, 4, 8), 256, 0, stream>>>(
        Wv16, DIM, 0, v16, DIM, (long)SEQ * DIM,
        vpT16, SEQ, (long)DIM * SEQ, DIM, c);

    // K4: softmax — fp16 dots in, fp32 attn out (NT) + fp16 normalize in place
    softmax_rows<<<dim3(BATCH * SEQ), 256, 0, stream>>>(dots16, attn);

    // K6: out[n,e] = sum_m attn[n,m]*vpT[e,m]  per batch -> fp32 out (NT)
    gemm_nt_f16<false><<<dim3(4, 16, 8), 256, 0, stream>>>(
        dots16, SEQ, (long)SEQ * SEQ, vpT16, SEQ, (long)DIM * SEQ,
        out, DIM, (long)SEQ * DIM, SEQ, 1.0f);
}